// Round 8
// baseline (1158.248 us; speedup 1.0000x reference)
//
#include <hip/hip_runtime.h>

#define NV   200000      // occupied voxels
#define CC   128         // channels
#define KOFF 27          // 3x3x3 offsets
#define CAPK 42000       // per-k T capacity (m_k ~ 39.6k +- 178; +13 sigma)
#define TROWS (26 * CAPK + NV)   // 1,292,000 rows

typedef unsigned short u16;
typedef __attribute__((ext_vector_type(4))) float f32x4;
typedef __attribute__((ext_vector_type(8))) short bf16x8;

__device__ __forceinline__ u16 f2bf(float f) {
    unsigned u = __float_as_uint(f);
    u += 0x7fffu + ((u >> 16) & 1u);          // RNE
    return (u16)(u >> 16);
}
__device__ __forceinline__ size_t tbase(int k) {   // T segment base row for k
    return (size_t)k * CAPK + (k > 13 ? (NV - CAPK) : 0);
}

// global -> LDS direct DMA, 16B per lane; LDS dest = uniform base + lane*16
#define GLOAD16(gp, lp)                                                        \
    __builtin_amdgcn_global_load_lds(                                          \
        (const __attribute__((address_space(1))) void*)(gp),                   \
        (__attribute__((address_space(3))) void*)(lp), 16, 0, 0)

// ---------------------------------------------------------------------------
// rmap[k][o] = rank of o within the (sorted) valid-output list of offset k,
// or -1. out_idx entries are distinct per k -> race-free scatter.
__global__ void rmap_kernel(const int* __restrict__ iout,
                            int* __restrict__ rmap) {
    int t = blockIdx.x * 256 + threadIdx.x;
    if (t >= KOFF * NV) return;
    int o = iout[t];
    if (o < NV) {
        int k = t / NV;
        rmap[(size_t)k * NV + o] = t - k * NV;
    }
}

// fp32 -> bf16, 4 elems/thread
__global__ void cvt_kernel(const float* __restrict__ src,
                           u16* __restrict__ dst, int n4) {
    int i = blockIdx.x * 256 + threadIdx.x;
    if (i >= n4) return;
    float4 v = ((const float4*)src)[i];
    ushort4 o;
    o.x = f2bf(v.x); o.y = f2bf(v.y); o.z = f2bf(v.z); o.w = f2bf(v.w);
    ((ushort4*)dst)[i] = o;
}

// Pack W[k][kpos][col] fp32 into fragment-linear bf16:
// Wp[(k*nks+ks)*8 + cf][lane][j] = W[k][ks*32 + (lane>>4)*8 + j][cf*16 + (lane&15)]
__global__ void packw_kernel(const float* __restrict__ W,
                             u16* __restrict__ Wp, int cin, int total) {
    int t = blockIdx.x * 256 + threadIdx.x;
    if (t >= total) return;
    int j  = t & 7;
    int l  = (t >> 3) & 63;
    int cf = (t >> 9) & 7;
    int sk = t >> 12;                 // k*nks + ks
    int nks = cin >> 5;
    int k  = sk / nks;
    int ks = sk - k * nks;
    int kpos = ks * 32 + (l >> 4) * 8 + j;
    int col  = cf * 16 + (l & 15);
    Wp[t] = f2bf(W[((size_t)k * cin + kpos) * CC + col]);
}

// ---------------------------------------------------------------------------
// Phase A: per offset k (blockIdx.y), dense tall GEMM over the COMPACTED
// pair list:  T[tb(k)+t] = feat[in_idx[k][t]] @ W_k[:, hc*64 .. +63].
// 128-row x 64-col tile / block, 4 waves (32x64 each), BK=32, double-buffered
// LDS, r4-proven A-chunk swizzle + glds staging. k fixed -> gather indices
// loaded once. Fully-padded tiles (out_idx[k][r0]==N sentinel) exit instantly.
template <int NKS>
__global__ __launch_bounds__(256, 4)
void convA_kernel(const u16* __restrict__ f0, const u16* __restrict__ f1,
                  const u16* __restrict__ Wp, const int* __restrict__ iidx,
                  const int* __restrict__ oidx, u16* __restrict__ T, int hc) {
    const int k  = blockIdx.y;
    const int r0 = blockIdx.x * 128;
    if (oidx[(size_t)k * NV + r0] >= NV) return;    // tile entirely padding

    __shared__ u16 Ab[2][512 * 8];    // 128 rows x 32 ch, chunk-swizzled, 8 KiB ea
    __shared__ u16 Bb[2][4][64][8];   // 4 col-frags (this half), 4 KiB ea

    const int tid = threadIdx.x;
    const int l   = tid & 63;
    const int w   = tid >> 6;

    // staging geometry (r4): wave w issues A-instrs j=2w,2w+1; instr j covers
    // slots j*64+l -> row = j*16 + (l>>2), source chunk = (l&3)^((l>>3)&3)
    const int qA  = (l & 3) ^ ((l >> 3) & 3);
    int ra = r0 + 32 * w + (l >> 2); if (ra >= NV) ra = NV - 1;
    int rb = ra + 16;                if (rb >= NV) rb = NV - 1;
    const int gA = iidx[(size_t)k * NV + ra];   // padding rows have in_idx=0
    const int gB = iidx[(size_t)k * NV + rb];

    f32x4 acc[2][4] = {};

    auto stage = [&](int ks, int buf) {
        const u16* base;
        int slice;
        if constexpr (NKS == 8) {                 // concat: 0-3 = x, 4-7 = h
            base  = (ks < 4) ? f0 : f1;
            slice = (ks & 3) * 32;
        } else {
            base  = f0;
            slice = ks * 32;
        }
        GLOAD16(base + (size_t)gA * CC + slice + qA * 8, &Ab[buf][(2 * w) * 512]);
        GLOAD16(base + (size_t)gB * CC + slice + qA * 8, &Ab[buf][(2 * w + 1) * 512]);
        const u16* wsrc = Wp + ((size_t)(k * NKS + ks) * 8 + hc * 4 + w) * 512 + l * 8;
        GLOAD16(wsrc, &Bb[buf][w][0][0]);
    };

    auto compute = [&](int buf) {
        bf16x8 a[2], b[4];
        const int q = l >> 4;
#pragma unroll
        for (int rf = 0; rf < 2; ++rf) {
            int rl = w * 32 + rf * 16 + (l & 15);
            int ci = rl * 4 + (q ^ ((rl >> 1) & 3));
            a[rf] = *(const bf16x8*)&Ab[buf][ci * 8];
        }
#pragma unroll
        for (int c = 0; c < 4; ++c)
            b[c] = *(const bf16x8*)&Bb[buf][c][l][0];
#pragma unroll
        for (int rf = 0; rf < 2; ++rf)
#pragma unroll
            for (int c = 0; c < 4; ++c)
                acc[rf][c] = __builtin_amdgcn_mfma_f32_16x16x32_bf16(
                    a[rf], b[c], acc[rf][c], 0, 0, 0);
    };

    stage(0, 0);
    __syncthreads();
#pragma unroll
    for (int s = 0; s < NKS; ++s) {
        if (s + 1 < NKS) stage(s + 1, (s + 1) & 1);
        compute(s & 1);
        __syncthreads();
    }

    // epilogue: C/D layout col=lane&15, row=(lane>>4)*4+reg  [m89-verified]
    const int   cap = (k == 13) ? NV : CAPK;     // never write past segment
    const size_t tb = tbase(k);
#pragma unroll
    for (int rf = 0; rf < 2; ++rf) {
        int rbase = r0 + w * 32 + rf * 16 + (l >> 4) * 4;
#pragma unroll
        for (int i = 0; i < 4; ++i) {
            int trow = rbase + i;
            if (trow < cap) {
                u16* dst = T + (tb + trow) * 64 + (l & 15);
#pragma unroll
                for (int c = 0; c < 4; ++c)
                    dst[c * 16] = f2bf(acc[rf][c][i]);
            }
        }
    }
}

// ---------------------------------------------------------------------------
// Phase B: out[o][hc*64+..] = bias + sum over valid k of T[tb(k)+rmap[k][o]].
// 256 rows/block, 1 thread per row x 64 cols. rmap block-staged in LDS.
// Memory-bound gather-reduce; rank lists are sorted -> near-sequential reads.
template <int ACT, int OUT16>
__global__ __launch_bounds__(256, 4)
void convB_kernel(const u16* __restrict__ T, const int* __restrict__ rmap,
                  const float* __restrict__ bias,
                  float* __restrict__ out32, u16* __restrict__ out16, int hc) {
    __shared__ int   sm[KOFF * 256];
    __shared__ float sb[64];
    const int r0  = blockIdx.x * 256;
    const int tid = threadIdx.x;

    for (int j = tid; j < KOFF * 256; j += 256) {
        int k = j >> 8, rr = j & 255;
        int o = r0 + rr;
        sm[j] = (o < NV) ? rmap[(size_t)k * NV + o] : -1;
    }
    if (tid < 64) sb[tid] = bias[hc * 64 + tid];
    __syncthreads();

    float acc[64];
#pragma unroll
    for (int j = 0; j < 64; ++j) acc[j] = sb[j];

    for (int k = 0; k < KOFF; ++k) {
        int t = sm[k * 256 + tid];
        if (t < 0) continue;
        const u16* p = T + (tbase(k) + (size_t)t) * 64;
#pragma unroll
        for (int c = 0; c < 8; ++c) {
            bf16x8 v = *(const bf16x8*)(p + c * 8);
#pragma unroll
            for (int j = 0; j < 8; ++j) {
                unsigned uu = ((unsigned)(u16)v[j]) << 16;
                acc[c * 8 + j] += __uint_as_float(uu);
            }
        }
    }

    const int r = r0 + tid;
    if (r < NV) {
        if constexpr (OUT16) {
            u16* d = out16 + (size_t)r * CC + hc * 64;
#pragma unroll
            for (int c = 0; c < 8; ++c) {
                bf16x8 pk;
#pragma unroll
                for (int j = 0; j < 8; ++j) {
                    float v = acc[c * 8 + j];
                    if constexpr (ACT) v = fmaxf(v, 0.f);
                    pk[j] = (short)f2bf(v);
                }
                *(bf16x8*)(d + c * 8) = pk;
            }
        } else {
            float* d = out32 + (size_t)r * CC + hc * 64;
#pragma unroll
            for (int c = 0; c < 16; ++c) {
                float4 pk;
                float v0 = acc[c * 4 + 0], v1 = acc[c * 4 + 1];
                float v2 = acc[c * 4 + 2], v3 = acc[c * 4 + 3];
                if constexpr (ACT) {
                    v0 = fmaxf(v0, 0.f); v1 = fmaxf(v1, 0.f);
                    v2 = fmaxf(v2, 0.f); v3 = fmaxf(v3, 0.f);
                }
                pk.x = v0; pk.y = v1; pk.z = v2; pk.w = v3;
                *(float4*)(d + c * 4) = pk;
            }
        }
    }
}

// ---------------------------------------------------------------------------
extern "C" void kernel_launch(void* const* d_in, const int* in_sizes, int n_in,
                              void* d_out, int out_size, void* d_ws, size_t ws_size,
                              hipStream_t stream) {
    (void)in_sizes; (void)n_in; (void)out_size; (void)ws_size;
    const float* xF  = (const float*)d_in[0];
    const float* xgF = (const float*)d_in[1];
    const float* W0  = (const float*)d_in[2];
    const float* b0  = (const float*)d_in[3];
    const float* W1  = (const float*)d_in[4];
    const float* b1  = (const float*)d_in[5];
    const float* W2  = (const float*)d_in[6];
    const float* b2  = (const float*)d_in[7];
    const int* iin   = (const int*)d_in[8];
    const int* iout  = (const int*)d_in[9];
    float* out = (float*)d_out;
    char* ws = (char*)d_ws;

    size_t off = 0;
    int* rmap  = (int*)(ws + off);  off += (size_t)KOFF * NV * 4;          // 21.6 MB
    u16* F0    = (u16*)(ws + off);  off += (size_t)NV * CC * 2;            // xg16 -> h1
    u16* F1    = (u16*)(ws + off);  off += (size_t)NV * CC * 2;            // h0
    u16* F2    = (u16*)(ws + off);  off += (size_t)NV * CC * 2;            // x16
    u16* WP0   = (u16*)(ws + off);  off += (size_t)KOFF * 128 * 128 * 2;
    u16* WP1   = (u16*)(ws + off);  off += (size_t)KOFF * 128 * 128 * 2;
    u16* WP2   = (u16*)(ws + off);  off += (size_t)KOFF * 256 * 128 * 2;
    u16* T     = (u16*)(ws + off);  off += (size_t)TROWS * 64 * 2;         // 165.4 MB
    // total ~344 MB of d_ws

    (void)hipMemsetAsync(rmap, 0xFF, (size_t)KOFF * NV * 4, stream);       // -1

    rmap_kernel<<<(KOFF * NV + 255) / 256, 256, 0, stream>>>(iout, rmap);
    cvt_kernel<<<(NV * CC / 4 + 255) / 256, 256, 0, stream>>>(xgF, F0, NV * CC / 4);
    cvt_kernel<<<(NV * CC / 4 + 255) / 256, 256, 0, stream>>>(xF,  F2, NV * CC / 4);
    packw_kernel<<<(KOFF * 128 * 128 + 255) / 256, 256, 0, stream>>>(W0, WP0, 128, KOFF * 128 * 128);
    packw_kernel<<<(KOFF * 128 * 128 + 255) / 256, 256, 0, stream>>>(W1, WP1, 128, KOFF * 128 * 128);
    packw_kernel<<<(KOFF * 256 * 128 + 255) / 256, 256, 0, stream>>>(W2, WP2, 256, KOFF * 256 * 128);

    const dim3 gA((NV + 127) / 128, KOFF);     // 1563 x 27
    const int  gB = (NV + 255) / 256;          // 782

    // conv0: h0 = xg (*) W0 + b0            -> F1 (bf16)
    for (int hc = 0; hc < 2; ++hc) {
        convA_kernel<4><<<gA, 256, 0, stream>>>(F0, F0, WP0, iin, iout, T, hc);
        convB_kernel<0, 1><<<gB, 256, 0, stream>>>(T, rmap, b0, nullptr, F1, hc);
    }
    // conv1: h1 = relu(h0 (*) W1 + b1)      -> F0 (bf16)
    for (int hc = 0; hc < 2; ++hc) {
        convA_kernel<4><<<gA, 256, 0, stream>>>(F1, F1, WP1, iin, iout, T, hc);
        convB_kernel<1, 1><<<gB, 256, 0, stream>>>(T, rmap, b1, nullptr, F0, hc);
    }
    // conv2: out = [x | h1] (*) W2 + b2     -> d_out (fp32)
    for (int hc = 0; hc < 2; ++hc) {
        convA_kernel<8><<<gA, 256, 0, stream>>>(F2, F0, WP2, iin, iout, T, hc);
        convB_kernel<0, 0><<<gB, 256, 0, stream>>>(T, rmap, b2, out, nullptr, hc);
    }
}